// Round 1
// 69.391 us; speedup vs baseline: 1.0058x; 1.0058x over previous
//
#include <hip/hip_runtime.h>
#include <hip/hip_bf16.h>
#include <math.h>

#define MODES 32
#define BLOCK 256
#define TWO_PI 6.283185307179586f
#define INV_2PI 0.15915494309189535f
#define LROWW 36   // padded row stride in 4B words (72 bf16, 144B: 16B-aligned)

typedef __attribute__((ext_vector_type(8))) short bf16x8;
typedef __attribute__((ext_vector_type(4))) float f32x4;

__device__ __forceinline__ unsigned int pk_bf16(float a, float b) {
    __hip_bfloat162 h = __float22bfloat162_rn(float2{a, b});
    union { __hip_bfloat162 v; unsigned int u; } cv; cv.v = h;
    return cv.u;
}

// hi = bf16(a)|bf16(b) packed; lo = bf16 of residuals
__device__ __forceinline__ void split2(float a, float b, unsigned int& hi, unsigned int& lo) {
    hi = pk_bf16(a, b);
    const float ha = __uint_as_float((hi & 0xFFFFu) << 16);
    const float hb = __uint_as_float(hi & 0xFFFF0000u);
    lo = pk_bf16(a - ha, b - hb);
}

// complex square in place (temps guard aliasing)
__device__ __forceinline__ void csq(float& r, float& i) {
    const float nr = fmaf(r, r, -(i * i));
    const float ni = 2.0f * r * i;
    r = nr; i = ni;
}

// (xr,xi) *= (mr,mi), alias-safe
__device__ __forceinline__ void cmul(float& xr, float& xi, float mr, float mi) {
    const float tr = fmaf(xr, mr, -(xi * mi));
    const float ti = fmaf(xr, mi, xi * mr);
    xr = tr; xi = ti;
}

// ---------------- MFMA path (L == 4096 = 64 x 64) ----------------
// K[h, 64*i + j] = sum_k A[i,k] * B[k,j],  k = 2*mode (+1)
// A[i,2n]=2*Re(dC_n*W_n^i), A[i,2n+1]=-2*Im(dC_n*W_n^i),  W = dA^64
// B[2n,j]=Re(dA_n^j),       B[2n+1,j]=Im(dA_n^j)
// Seeds via pure-FMA squaring ladder (no log/atan2/sincos): dA^(8*i8) and
// dC2*dA^(512*i8) by binary powering on the 3 bits of i8.
__global__ __launch_bounds__(BLOCK) void s4d_mfma(
    const float* __restrict__ log_dt,
    const float* __restrict__ C_real,
    const float* __restrict__ log_A_real,
    const float* __restrict__ A_imag,
    float* __restrict__ out)
{
    __shared__ __align__(16) unsigned int sAhi[64 * LROWW];
    __shared__ __align__(16) unsigned int sAlo[64 * LROWW];
    __shared__ __align__(16) unsigned int sBhi[64 * LROWW];  // BT[j][k]
    __shared__ __align__(16) unsigned int sBlo[64 * LROWW];

    const int h = blockIdx.x;
    const int t = threadIdx.x;
    const int mode = t & 31;
    const int i8   = t >> 5;       // 0..7

    // ---- per-thread discretization (redundant across i8 groups, cheap) ----
    const float dt = __expf(log_dt[h]);
    const float ar = -__expf(log_A_real[h * MODES + mode]);
    const float ai = A_imag[h * MODES + mode];
    const float dtAr = ar * dt, dtAi = ai * dt;
    const float den_r = 1.0f - 0.5f * dtAr, den_i = -0.5f * dtAi;
    const float num_r = 1.0f + 0.5f * dtAr, num_i =  0.5f * dtAi;
    const float inv = 1.0f / (den_r * den_r + den_i * den_i);
    const float Br =  dt * den_r * inv;
    const float Bi = -dt * den_i * inv;
    const float Cr = C_real[(h * MODES + mode) * 2 + 0];
    const float Ci = C_real[(h * MODES + mode) * 2 + 1];
    const float dcr2 = 2.0f * (Cr * Br - Ci * Bi);
    const float dci2 = 2.0f * (Cr * Bi + Ci * Br);
    const float dAr = (num_r * den_r + num_i * den_i) * inv;
    const float dAi = (num_i * den_r - num_r * den_i) * inv;

    // ---- squaring ladder: dA^2 .. dA^2048 (pure FMA, 11 complex squares) ----
    float cr_ = dAr, ci_ = dAi;
    csq(cr_, ci_);                                   // dA^2
    csq(cr_, ci_);                                   // dA^4
    csq(cr_, ci_); const float d8r    = cr_, d8i    = ci_;
    csq(cr_, ci_); const float d16r   = cr_, d16i   = ci_;
    csq(cr_, ci_); const float d32r   = cr_, d32i   = ci_;
    csq(cr_, ci_); const float Wr     = cr_, Wi     = ci_;   // dA^64
    csq(cr_, ci_);                                   // dA^128
    csq(cr_, ci_);                                   // dA^256
    csq(cr_, ci_); const float d512r  = cr_, d512i  = ci_;
    csq(cr_, ci_); const float d1024r = cr_, d1024i = ci_;
    csq(cr_, ci_); const float d2048r = cr_, d2048i = ci_;

    // ---- B seed = dA^(8*i8) via binary powering ----
    float br = (i8 & 1) ? d8r : 1.0f;
    float bi = (i8 & 1) ? d8i : 0.0f;
    cmul(br, bi, (i8 & 2) ? d16r : 1.0f, (i8 & 2) ? d16i : 0.0f);
    cmul(br, bi, (i8 & 4) ? d32r : 1.0f, (i8 & 4) ? d32i : 0.0f);

    // ---- A seed = dC2 * dA^(512*i8) = dC2 * W^(8*i8) ----
    float tr = (i8 & 1) ? d512r : 1.0f;
    float ti = (i8 & 1) ? d512i : 0.0f;
    cmul(tr, ti, (i8 & 2) ? d1024r : 1.0f, (i8 & 2) ? d1024i : 0.0f);
    cmul(tr, ti, (i8 & 4) ? d2048r : 1.0f, (i8 & 4) ? d2048i : 0.0f);
    float pr = dcr2 * tr - dci2 * ti;
    float pi = dcr2 * ti + dci2 * tr;

    int base = (i8 * 8) * LROWW + mode;
    #pragma unroll
    for (int b = 0; b < 8; ++b) {
        unsigned int hi, lo;
        split2(br, bi, hi, lo);
        sBhi[base] = hi; sBlo[base] = lo;
        split2(pr, -pi, hi, lo);
        sAhi[base] = hi; sAlo[base] = lo;
        // step B by dA, A by W
        cmul(br, bi, dAr, dAi);
        cmul(pr, pi, Wr, Wi);
        base += LROWW;
    }
    __syncthreads();

    // -------- MFMA: wave w computes rows [16w, 16w+16) of the 64x64 C --------
    const int wv   = t >> 6;
    const int lane = t & 63;
    const int c16  = lane & 15;
    const int quad = lane >> 4;

    const int arow = (wv * 16 + c16) * LROWW + quad * 4;
    const bf16x8 ah0 = *(const bf16x8*)&sAhi[arow];
    const bf16x8 ah1 = *(const bf16x8*)&sAhi[arow + 16];
    const bf16x8 al0 = *(const bf16x8*)&sAlo[arow];
    const bf16x8 al1 = *(const bf16x8*)&sAlo[arow + 16];

    float* op = out + ((size_t)h << 12) + (size_t)(wv * 16 + quad * 4) * 64 + c16;

    #pragma unroll
    for (int nt = 0; nt < 4; ++nt) {
        const int brow = (nt * 16 + c16) * LROWW + quad * 4;
        const bf16x8 bh0 = *(const bf16x8*)&sBhi[brow];
        const bf16x8 bh1 = *(const bf16x8*)&sBhi[brow + 16];
        const bf16x8 bl0 = *(const bf16x8*)&sBlo[brow];
        const bf16x8 bl1 = *(const bf16x8*)&sBlo[brow + 16];

        // two independent 3-deep chains instead of one 6-deep chain
        f32x4 acc0 = {0.f, 0.f, 0.f, 0.f};
        f32x4 acc1 = {0.f, 0.f, 0.f, 0.f};
        acc0 = __builtin_amdgcn_mfma_f32_16x16x32_bf16(ah0, bh0, acc0, 0, 0, 0);
        acc1 = __builtin_amdgcn_mfma_f32_16x16x32_bf16(ah1, bh1, acc1, 0, 0, 0);
        acc0 = __builtin_amdgcn_mfma_f32_16x16x32_bf16(ah0, bl0, acc0, 0, 0, 0);
        acc1 = __builtin_amdgcn_mfma_f32_16x16x32_bf16(ah1, bl1, acc1, 0, 0, 0);
        acc0 = __builtin_amdgcn_mfma_f32_16x16x32_bf16(al0, bh0, acc0, 0, 0, 0);
        acc1 = __builtin_amdgcn_mfma_f32_16x16x32_bf16(al1, bh1, acc1, 0, 0, 0);

        #pragma unroll
        for (int r = 0; r < 4; ++r)
            op[(size_t)r * 64 + nt * 16] = acc0[r] + acc1[r];
    }
}

// ---------------- fallback: stride-256 real recurrence (any L % 256 == 0) ----------------
__global__ __launch_bounds__(BLOCK) void s4d_recur(
    const float* __restrict__ log_dt, const float* __restrict__ C_real,
    const float* __restrict__ log_A_real, const float* __restrict__ A_imag,
    float* __restrict__ out, int L)
{
    const int h = blockIdx.x, tid = threadIdx.x;
    const int P = L / BLOCK;
    __shared__ float4 s_c0[MODES], s_c1[MODES];
    if (tid < MODES) {
        const int n = tid;
        const float dt = __expf(log_dt[h]);
        const float ar = -__expf(log_A_real[h * MODES + n]);
        const float ai = A_imag[h * MODES + n];
        const float dtAr = ar * dt, dtAi = ai * dt;
        const float den_r = 1.0f - 0.5f * dtAr, den_i = -0.5f * dtAi;
        const float num_r = 1.0f + 0.5f * dtAr, num_i = 0.5f * dtAi;
        const float inv = 1.0f / (den_r * den_r + den_i * den_i);
        const float Brr = dt * den_r * inv, Bii = -dt * den_i * inv;
        const float Cr = C_real[(h * MODES + n) * 2 + 0];
        const float Ci = C_real[(h * MODES + n) * 2 + 1];
        const float dCr = Cr * Brr - Ci * Bii, dCi = Cr * Bii + Ci * Brr;
        const float dAr = (num_r * den_r + num_i * den_i) * inv;
        const float dAi = (num_i * den_r - num_r * den_i) * inv;
        const float xr = 0.5f * __logf(dAr * dAr + dAi * dAi);
        const float rev = atan2f(dAi, dAr) * INV_2PI;
        const float S = (float)BLOCK;
        const float mag = __expf(xr * S);
        float tt = rev * S; tt -= rintf(tt);
        float ws, wc; __sincosf(tt * TWO_PI, &ws, &wc);
        s_c0[n] = make_float4(xr, rev, 2.0f * dCr, 2.0f * dCi);
        s_c1[n] = make_float4(mag * wc, mag * ws, 2.0f * mag * wc, -(mag * mag));
    }
    __syncthreads();
    float m0[MODES], m1[MODES], aS[MODES], bS[MODES];
    float acc0 = 0.f, acc1 = 0.f;
    const float lf = (float)tid;
    #pragma unroll
    for (int n = 0; n < MODES; ++n) {
        const float4 c0 = s_c0[n]; const float4 c1 = s_c1[n];
        const float er = __expf(c0.x * lf);
        float tt = c0.y * lf; tt -= rintf(tt);
        float sn, cs; __sincosf(tt * TWO_PI, &sn, &cs);
        const float pr = er * cs, pi = er * sn;
        const float v0 = fmaf(c0.z, pr, -c0.w * pi);
        const float qr = fmaf(pr, c1.x, -pi * c1.y);
        const float qi = fmaf(pr, c1.y, pi * c1.x);
        const float v1 = fmaf(c0.z, qr, -c0.w * qi);
        m0[n] = v0; m1[n] = v1; acc0 += v0; acc1 += v1;
        aS[n] = c1.z; bS[n] = c1.w;
    }
    float* outp = out + (size_t)h * (size_t)L + tid;
    outp[0] = acc0;
    if (P > 1) outp[BLOCK] = acc1;
    int p = 2;
    for (; p + 1 < P; p += 2) {
        float accA = 0.f, accB = 0.f;
        #pragma unroll
        for (int n = 0; n < MODES; ++n) {
            const float mA = fmaf(aS[n], m1[n], bS[n] * m0[n]);
            const float mB = fmaf(aS[n], mA, bS[n] * m1[n]);
            accA += mA; accB += mB; m0[n] = mA; m1[n] = mB;
        }
        outp[(size_t)p * BLOCK] = accA;
        outp[(size_t)(p + 1) * BLOCK] = accB;
    }
    if (p < P) {
        float accA = 0.f;
        #pragma unroll
        for (int n = 0; n < MODES; ++n) {
            const float mA = fmaf(aS[n], m1[n], bS[n] * m0[n]);
            accA += mA; m0[n] = m1[n]; m1[n] = mA;
        }
        outp[(size_t)p * BLOCK] = accA;
    }
}

extern "C" void kernel_launch(void* const* d_in, const int* in_sizes, int n_in,
                              void* d_out, int out_size, void* d_ws, size_t ws_size,
                              hipStream_t stream) {
    const float* log_dt     = (const float*)d_in[0];
    const float* C_real     = (const float*)d_in[1];
    const float* log_A_real = (const float*)d_in[2];
    const float* A_imag     = (const float*)d_in[3];
    float* out = (float*)d_out;

    const int H = in_sizes[0];
    const int L = out_size / H;

    if (L == 4096) {
        s4d_mfma<<<H, BLOCK, 0, stream>>>(log_dt, C_real, log_A_real, A_imag, out);
    } else {
        s4d_recur<<<H, BLOCK, 0, stream>>>(log_dt, C_real, log_A_real, A_imag, out, L);
    }
}